// Round 1
// 1201.738 us; speedup vs baseline: 1.0158x; 1.0158x over previous
//
#include <hip/hip_runtime.h>
#include <stdint.h>
#include <stddef.h>

#define B_DIM 2048
#define FIN   4096
#define FOUT  2048
#define NITER 10
#define SMIN  1e-5f

// fp8 pre-scales (exact powers of 2): Wn*2^14 <= ~17, h*2^8 <= 256 < 448 (e4m3 max)
#define WSCALE 16384.0f
#define HSCALE 256.0f
#define OUTSCALE (1.0f / 4194304.0f)   // 2^-22

typedef float floatx16 __attribute__((ext_vector_type(16)));
typedef short bf16x8   __attribute__((ext_vector_type(8)));

__device__ inline unsigned short f2bf(float f) {
    unsigned int u = __float_as_uint(f);
    u += 0x7fffu + ((u >> 16) & 1u);
    return (unsigned short)(u >> 16);
}
__device__ inline float bflo(unsigned int u) { return __uint_as_float(u << 16); }
__device__ inline float bfhi(unsigned int u) { return __uint_as_float(u & 0xffff0000u); }
__device__ inline unsigned int pack2(float a, float b) {
    return (unsigned int)f2bf(a) | ((unsigned int)f2bf(b) << 16);
}

__device__ inline void async16(const void* g, void* l) {
    __builtin_amdgcn_global_load_lds(
        (const __attribute__((address_space(1))) void*)g,
        (__attribute__((address_space(3))) void*)l, 16, 0, 0);
}

__device__ inline float block_row_sum(float v) {
    #pragma unroll
    for (int o = 32; o > 0; o >>= 1) v += __shfl_down(v, o, 64);
    __shared__ float red[4];
    const int lane = threadIdx.x & 63, w = threadIdx.x >> 6;
    if (lane == 0) red[w] = v;
    __syncthreads();
    return red[0] + red[1] + red[2] + red[3];
}

// Wn = clip(W,1e-5)/rowsum -> bf16 (FOUT x FIN)  [bf16 master, used by GEMM2 + fp8 transpose]
__global__ __launch_bounds__(256) void k_norm_w(const float* __restrict__ W,
                                                unsigned short* __restrict__ Wn) {
    const int row = blockIdx.x;
    const float4* src = (const float4*)(W + (size_t)row * FIN);
    float4 vals[4];
    float s = 0.f;
    #pragma unroll
    for (int i = 0; i < 4; ++i) {
        float4 v = src[i * 256 + threadIdx.x];
        v.x = fmaxf(v.x, SMIN); v.y = fmaxf(v.y, SMIN);
        v.z = fmaxf(v.z, SMIN); v.w = fmaxf(v.w, SMIN);
        vals[i] = v;
        s += (v.x + v.y) + (v.z + v.w);
    }
    s = block_row_sum(s);
    const float inv = 1.f / fmaxf(s, 1e-20f);
    ushort4* dst = (ushort4*)(Wn + (size_t)row * FIN);
    #pragma unroll
    for (int i = 0; i < 4; ++i) {
        float4 v = vals[i];
        ushort4 o;
        o.x = f2bf(v.x * inv); o.y = f2bf(v.y * inv);
        o.z = f2bf(v.z * inv); o.w = f2bf(v.w * inv);
        dst[i * 256 + threadIdx.x] = o;
    }
}

// xn = x / rowsum(x) -> bf16 packed (B x FIN)
__global__ __launch_bounds__(256) void k_norm_x(const float* __restrict__ x,
                                                unsigned int* __restrict__ xnb) {
    const int row = blockIdx.x;
    const float4* src = (const float4*)(x + (size_t)row * FIN);
    float4 vals[4];
    float s = 0.f;
    #pragma unroll
    for (int j = 0; j < 2; ++j) {
        const int idx = j * 256 + threadIdx.x;
        float4 a = src[2 * idx], b = src[2 * idx + 1];
        vals[2 * j] = a; vals[2 * j + 1] = b;
        s += (fabsf(a.x) + fabsf(a.y)) + (fabsf(a.z) + fabsf(a.w));
        s += (fabsf(b.x) + fabsf(b.y)) + (fabsf(b.z) + fabsf(b.w));
    }
    s = block_row_sum(s);
    const float inv = 1.f / fmaxf(s, 1e-20f);
    uint4* dst = (uint4*)(xnb + (size_t)row * (FIN / 2));
    #pragma unroll
    for (int j = 0; j < 2; ++j) {
        float4 a = vals[2 * j], b = vals[2 * j + 1];
        uint4 o;
        o.x = pack2(a.x * inv, a.y * inv);
        o.y = pack2(a.z * inv, a.w * inv);
        o.z = pack2(b.x * inv, b.y * inv);
        o.w = pack2(b.z * inv, b.w * inv);
        dst[j * 256 + threadIdx.x] = o;
    }
}

// WnT8[i][o] = fp8(Wn[o][i] * 2^14)   (B operand of GEMM1, fp8 e4m3)
__global__ __launch_bounds__(256) void k_transpose_fp8(const unsigned short* __restrict__ src,
                                                       unsigned char* __restrict__ dst) {
    __shared__ unsigned short tile[32][33];
    const int bi = blockIdx.x * 32, bo = blockIdx.y * 32;
    const int tx = threadIdx.x, ty = threadIdx.y;  // (32,8)
    #pragma unroll
    for (int j = 0; j < 4; ++j)
        tile[ty + j * 8][tx] = src[(size_t)(bo + ty + j * 8) * FIN + bi + tx];
    __syncthreads();
    #pragma unroll
    for (int j = 0; j < 4; ++j) {
        const float v = bflo((unsigned int)tile[tx][ty + j * 8]) * WSCALE;
        const unsigned int b = (unsigned int)__builtin_amdgcn_cvt_pk_fp8_f32(v, v, 0, false) & 0xffu;
        dst[(size_t)(bi + ty + j * 8) * FOUT + bo + tx] = (unsigned char)b;
    }
}

// h0 = 1/FOUT: fp32 master + fp8(h*2^8) = fp8(0.125) = 0x20 exactly
__global__ __launch_bounds__(256) void k_init_h(float* __restrict__ h,
                                                unsigned int* __restrict__ h8u) {
    const int i = blockIdx.x * blockDim.x + threadIdx.x;
    const float hv = 1.f / (float)FOUT;
    float4 v; v.x = hv; v.y = hv; v.z = hv; v.w = hv;
    ((float4*)h)[i] = v;
    h8u[i] = 0x20202020u;
}

// GEMM1 (fp8): rec_z = (h8 * WnT8^T) * 2^-22 -> bf16 partials.
// NT, split-K, 128x128 tile, BK=64, 4 waves each 64x64 = 2x2 of
// v_mfma_f32_32x32x16_fp8_fp8 (K=16, i64 operands = 8 fp8/lane, k=half*8+j).
__global__ __launch_bounds__(256) void k_gemm_fp8(const unsigned char* __restrict__ A,
                                                  const unsigned char* __restrict__ Bm,
                                                  unsigned short* __restrict__ C,
                                                  int N, int K, int Ksub) {
    __shared__ __align__(16) unsigned char As[128 * 64];  // 8 KB
    __shared__ __align__(16) unsigned char Bs[128 * 64];  // 8 KB
    const int tid  = threadIdx.x;
    const int wave = tid >> 6;
    const int lane = tid & 63;
    const int bm = blockIdx.y * 128;
    const int bn = blockIdx.x * 128;
    const int kz = blockIdx.z * Ksub;
    const int wr = (wave >> 1) * 64;
    const int wc = (wave & 1) * 64;
    const int l31 = lane & 31;
    const int half = lane >> 5;

    floatx16 acc[2][2] = {};

    const int lr = lane >> 2;
    const int ks = ((lane & 3) ^ ((lane >> 3) & 3)) * 16;  // bytes
    const unsigned char* ga = A  + (size_t)(bm + wave * 32 + lr) * K + ks;
    const unsigned char* gb = Bm + (size_t)(bn + wave * 32 + lr) * K + ks;

    for (int k0 = kz; k0 < kz + Ksub; k0 += 64) {
        __syncthreads();
        #pragma unroll
        for (int j = 0; j < 2; ++j) {
            async16(ga + (size_t)j * 16 * K + k0, &As[wave * 2048 + j * 1024]);
            async16(gb + (size_t)j * 16 * K + k0, &Bs[wave * 2048 + j * 1024]);
        }
        __syncthreads();

        const int sw = (l31 >> 1) & 3;
        #pragma unroll
        for (int kk = 0; kk < 4; ++kk) {
            const int off = ((kk ^ sw) << 4) + (half << 3);
            long long af[2], bf[2];
            #pragma unroll
            for (int t = 0; t < 2; ++t) {
                af[t] = *(const long long*)&As[(wr + t * 32 + l31) * 64 + off];
                bf[t] = *(const long long*)&Bs[(wc + t * 32 + l31) * 64 + off];
            }
            #pragma unroll
            for (int mt = 0; mt < 2; ++mt)
                #pragma unroll
                for (int nt = 0; nt < 2; ++nt)
                    acc[mt][nt] = __builtin_amdgcn_mfma_f32_32x32x16_fp8_fp8(
                        af[mt], bf[nt], acc[mt][nt], 0, 0, 0);
        }
    }

    unsigned short* Cz = C + (size_t)blockIdx.z * B_DIM * N;
    const int row0 = 4 * half;
    #pragma unroll
    for (int mt = 0; mt < 2; ++mt) {
        #pragma unroll
        for (int nt = 0; nt < 2; ++nt) {
            #pragma unroll
            for (int reg = 0; reg < 16; ++reg) {
                const int rr = bm + wr + mt * 32 + row0 + (reg & 3) + 8 * (reg >> 2);
                const int cc = bn + wc + nt * 32 + l31;
                Cz[(size_t)rr * N + cc] = f2bf(acc[mt][nt][reg] * OUTSCALE);
            }
        }
    }
}

// GEMM2 (bf16), R5: 256x256 tile, 8-wave (2Mx4N), BK=64, double-buffered LDS
// (128 KB), 4-phase-per-K-tile schedule with counted vmcnt (T2+T3+T4+T5 combo
// per the 8-phase template). Per-wave output 128x64 = 4x2 of
// v_mfma_f32_32x32x16_bf16 x 4 k-steps.
//
// LDS: sbuf[dbuf][op][half][128][64] bf16; staged linearly by global_load_lds
// with PRE-SWIZZLED global source: 16B slot s at row r holds global slot
// s^(r&7). Fragment ds_read_b128 applies the same XOR -> 8 touches/bank
// (conflict-free minimum).
//
// Phase schedule per K-tile group kt (dbuf d=kt&1), reads 12/4/8/0:
//   P1: ds A[m0,1][ks0-3]+B[n][ks0,1]; stage A-h0(kt+1); MFMA m01 x ks01
//   P2: ds B[n][ks2,3];                stage A-h1(kt+1); MFMA m01 x ks23
//   P3: ds A[m2,3][ks0-3];             stage B-h0(kt+2); MFMA m23 x ks01
//   P4: (no reads)                     stage B-h1(kt+2); MFMA m23 x ks23
//   boundary: s_waitcnt vmcnt(4)  (only the 2 half-tiles staged at P3/P4
//   stay in flight; they aren't consumed until group kt+2)
// Region-retirement proof: B region of d fully read by end-P2 (stage at P3 ok);
// A region of d fully read by end-P3 (restaged at P1/P2 of NEXT group).
// Raw s_barrier throughout (no __syncthreads -> no vmcnt(0) drain).
__global__ __launch_bounds__(512, 2) void k_gemm_nt256(const unsigned short* __restrict__ A,
                                                       const unsigned short* __restrict__ Bm,
                                                       float* __restrict__ C,
                                                       int N, int K, int Ksub) {
    __shared__ __align__(16) unsigned short sbuf[2][2][2][128 * 64];  // 128 KB
    char* sb = (char*)sbuf;

    const int t    = threadIdx.x;
    const int lane = t & 63;
    const int wid  = t >> 6;        // 0..7
    const int wm   = wid >> 2;      // 0..1 (M half)
    const int wn   = wid & 3;       // 0..3 (N quarter)
    const int l31  = lane & 31;

    const int bm = blockIdx.y * 256;
    const int bn = blockIdx.x * 256;
    const int kz = blockIdx.z * Ksub;
    const int NT = Ksub >> 6;       // K-tiles per block (>=2)

    // fragment-read lane constants: slot16 = (ks*2 + (lane>>5)) ^ (lane&7)
    int slotk[4];
    #pragma unroll
    for (int ks = 0; ks < 4; ++ks)
        slotk[ks] = ((((ks << 1) + (lane >> 5)) ^ (lane & 7)) << 4);
    const int arow = l31 * 128;     // row byte offset within a half-region

    // staging lane constants: thread t covers LDS bytes j*8192 + t*16 of a
    // 16KB half-region -> srow = j*64 + (t>>3), src slot = (t&7) ^ (srow&7)
    const int srow  = t >> 3;
    const int scole = (((t & 7) ^ ((t >> 3) & 7)) << 3);  // element offset
    const int ldst  = wid << 10;                          // wave-uniform base

    auto stage = [&](const unsigned short* g, int brow, int op, int h, int kt) {
        if (kt >= NT) return;
        const unsigned short* p = g + (size_t)(brow + h * 128 + srow) * K
                                    + (kz + (kt << 6)) + scole;
        char* r = sb + (kt & 1) * 65536 + op * 32768 + h * 16384 + ldst;
        async16(p, r);
        async16(p + (size_t)64 * K, r + 8192);
    };

    floatx16 acc[4][2] = {};

    // prologue: S0.B0,B1,A0,A1, S1.B0,B1 (12 loads); keep last 4 in flight
    stage(Bm, bn, 1, 0, 0); stage(Bm, bn, 1, 1, 0);
    stage(A,  bm, 0, 0, 0); stage(A,  bm, 0, 1, 0);
    stage(Bm, bn, 1, 0, 1); stage(Bm, bn, 1, 1, 1);
    asm volatile("s_waitcnt vmcnt(4)" ::: "memory");
    __builtin_amdgcn_s_barrier();

    for (int kt = 0; kt < NT; ++kt) {
        const char* Ab = sb + (kt & 1) * 65536 + wm * 16384 + arow;
        const char* Bb = sb + (kt & 1) * 65536 + 32768 + wn * 8192 + arow;
        bf16x8 fa[2][4], fb[2][4];

        // ---- P1: 12 ds_reads; stage A-h0(kt+1); MFMA m0,1 x ks0,1 ----
        #pragma unroll
        for (int ks = 0; ks < 4; ++ks) {
            fa[0][ks] = *(const bf16x8*)(Ab + slotk[ks]);
            fa[1][ks] = *(const bf16x8*)(Ab + 4096 + slotk[ks]);
        }
        #pragma unroll
        for (int ks = 0; ks < 2; ++ks) {
            fb[0][ks] = *(const bf16x8*)(Bb + slotk[ks]);
            fb[1][ks] = *(const bf16x8*)(Bb + 4096 + slotk[ks]);
        }
        stage(A, bm, 0, 0, kt + 1);
        __builtin_amdgcn_s_barrier();
        asm volatile("s_waitcnt lgkmcnt(0)" ::: "memory");
        __builtin_amdgcn_sched_barrier(0);
        __builtin_amdgcn_s_setprio(1);
        #pragma unroll
        for (int i = 0; i < 2; ++i)
            #pragma unroll
            for (int n = 0; n < 2; ++n)
                #pragma unroll
                for (int ks = 0; ks < 2; ++ks)
                    acc[i][n] = __builtin_amdgcn_mfma_f32_32x32x16_bf16(
                        fa[i][ks], fb[n][ks], acc[i][n], 0, 0, 0);
        __builtin_amdgcn_s_setprio(0);
        __builtin_amdgcn_s_barrier();

        // ---- P2: 4 ds_reads; stage A-h1(kt+1); MFMA m0,1 x ks2,3 ----
        #pragma unroll
        for (int ks = 2; ks < 4; ++ks) {
            fb[0][ks] = *(const bf16x8*)(Bb + slotk[ks]);
            fb[1][ks] = *(const bf16x8*)(Bb + 4096 + slotk[ks]);
        }
        stage(A, bm, 0, 1, kt + 1);
        __builtin_amdgcn_s_barrier();
        asm volatile("s_waitcnt lgkmcnt(0)" ::: "memory");
        __builtin_amdgcn_sched_barrier(0);
        __builtin_amdgcn_s_setprio(1);
        #pragma unroll
        for (int i = 0; i < 2; ++i)
            #pragma unroll
            for (int n = 0; n < 2; ++n)
                #pragma unroll
                for (int ks = 2; ks < 4; ++ks)
                    acc[i][n] = __builtin_amdgcn_mfma_f32_32x32x16_bf16(
                        fa[i][ks], fb[n][ks], acc[i][n], 0, 0, 0);
        __builtin_amdgcn_s_setprio(0);
        __builtin_amdgcn_s_barrier();

        // ---- P3: 8 ds_reads (A m2,3 -> fa); stage B-h0(kt+2); MFMA m2,3 x ks0,1
        #pragma unroll
        for (int ks = 0; ks < 4; ++ks) {
            fa[0][ks] = *(const bf16x8*)(Ab + 8192 + slotk[ks]);
            fa[1][ks] = *(const bf16x8*)(Ab + 12288 + slotk[ks]);
        }
        stage(Bm, bn, 1, 0, kt + 2);
        __builtin_amdgcn_s_barrier();
        asm volatile("s_waitcnt lgkmcnt(0)" ::: "memory");
        __builtin_amdgcn_sched_barrier(0);
        __builtin_amdgcn_s_setprio(1);
        #pragma unroll
        for (int i = 0; i < 2; ++i)
            #pragma unroll
            for (int n = 0; n < 2; ++n)
                #pragma unroll
                for (int ks = 0; ks < 2; ++ks)
                    acc[2 + i][n] = __builtin_amdgcn_mfma_f32_32x32x16_bf16(
                        fa[i][ks], fb[n][ks], acc[2 + i][n], 0, 0, 0);
        __builtin_amdgcn_s_setprio(0);
        __builtin_amdgcn_s_barrier();

        // ---- P4: 0 reads; stage B-h1(kt+2); MFMA m2,3 x ks2,3; boundary vmcnt
        stage(Bm, bn, 1, 1, kt + 2);
        __builtin_amdgcn_s_barrier();
        __builtin_amdgcn_s_setprio(1);
        #pragma unroll
        for (int i = 0; i < 2; ++i)
            #pragma unroll
            for (int n = 0; n < 2; ++n)
                #pragma unroll
                for (int ks = 2; ks < 4; ++ks)
                    acc[2 + i][n] = __builtin_amdgcn_mfma_f32_32x32x16_bf16(
                        fa[i][ks], fb[n][ks], acc[2 + i][n], 0, 0, 0);
        __builtin_amdgcn_s_setprio(0);
        if (kt + 2 < NT) {
            asm volatile("s_waitcnt vmcnt(4)" ::: "memory");
        } else {
            asm volatile("s_waitcnt vmcnt(0)" ::: "memory");
        }
        __builtin_amdgcn_sched_barrier(0);
        __builtin_amdgcn_s_barrier();
    }

    // C/D (verified m74/m101): col = lane&31, row = (reg&3)+8*(reg>>2)+4*(lane>>5)
    float* Cz = C + (size_t)blockIdx.z * B_DIM * N;
    const int r0 = bm + wm * 128 + 4 * (lane >> 5);
    const int c0 = bn + wn * 64 + l31;
    #pragma unroll
    for (int m = 0; m < 4; ++m) {
        #pragma unroll
        for (int n = 0; n < 2; ++n) {
            #pragma unroll
            for (int reg = 0; reg < 16; ++reg) {
                const int rr = r0 + m * 32 + (reg & 3) + 8 * (reg >> 2);
                Cz[(size_t)rr * N + (c0 + n * 32)] = acc[m][n][reg];
            }
        }
    }
}

// recon = sum of bf16 partials; s = rowsum(clip); r = xn*s/clip -> bf16
__global__ __launch_bounds__(256) void k_make_ratio(const unsigned short* __restrict__ rec,
                                                    int nparts,
                                                    const unsigned int* __restrict__ xnb,
                                                    unsigned int* __restrict__ r) {
    const int row = blockIdx.x;
    float v[16];
    float s = 0.f;
    #pragma unroll
    for (int g = 0; g < 2; ++g) {
        const int idx = g * 256 + threadIdx.x;
        uint4 u = ((const uint4*)(rec + (size_t)row * FIN))[idx];
        float* p = v + g * 8;
        p[0] = bflo(u.x); p[1] = bfhi(u.x); p[2] = bflo(u.y); p[3] = bfhi(u.y);
        p[4] = bflo(u.z); p[5] = bfhi(u.z); p[6] = bflo(u.w); p[7] = bfhi(u.w);
        for (int z = 1; z < nparts; ++z) {
            uint4 q = ((const uint4*)(rec + (size_t)z * B_DIM * FIN + (size_t)row * FIN))[idx];
            p[0] += bflo(q.x); p[1] += bfhi(q.x); p[2] += bflo(q.y); p[3] += bfhi(q.y);
            p[4] += bflo(q.z); p[5] += bfhi(q.z); p[6] += bflo(q.w); p[7] += bfhi(q.w);
        }
        #pragma unroll
        for (int e = 0; e < 8; ++e) { p[e] = fmaxf(p[e], SMIN); s += p[e]; }
    }
    s = block_row_sum(s);
    #pragma unroll
    for (int g = 0; g < 2; ++g) {
        const int idx = g * 256 + threadIdx.x;
        uint4 xu = ((const uint4*)(xnb + (size_t)row * (FIN / 2)))[idx];
        float* p = v + g * 8;
        uint4 o;
        o.x = pack2(bflo(xu.x) * s / p[0], bfhi(xu.x) * s / p[1]);
        o.y = pack2(bflo(xu.y) * s / p[2], bfhi(xu.y) * s / p[3]);
        o.z = pack2(bflo(xu.z) * s / p[4], bfhi(xu.z) * s / p[5]);
        o.w = pack2(bflo(xu.w) * s / p[6], bfhi(xu.w) * s / p[7]);
        ((uint4*)(r + (size_t)row * (FIN / 2)))[idx] = o;
    }
}

// upd = sum fp32 partials; t = clip(h*upd); h' = t/rowsum(t); fp32 master + fp8(h*2^8)
__global__ __launch_bounds__(256) void k_update_h(const float* __restrict__ hin,
                                                  const float* __restrict__ upd,
                                                  int nparts,
                                                  float* __restrict__ hout,
                                                  unsigned int* __restrict__ h8u) {
    const int row = blockIdx.x;
    const float4* hp = (const float4*)(hin + (size_t)row * FOUT);
    float4 vals[2];
    float s = 0.f;
    #pragma unroll
    for (int i = 0; i < 2; ++i) {
        const int idx = i * 256 + threadIdx.x;
        float4 hv = hp[idx];
        float4 uv = ((const float4*)(upd + (size_t)row * FOUT))[idx];
        for (int z = 1; z < nparts; ++z) {
            float4 p = ((const float4*)(upd + (size_t)z * B_DIM * FOUT + (size_t)row * FOUT))[idx];
            uv.x += p.x; uv.y += p.y; uv.z += p.z; uv.w += p.w;
        }
        float4 v;
        v.x = fmaxf(hv.x * uv.x, SMIN);
        v.y = fmaxf(hv.y * uv.y, SMIN);
        v.z = fmaxf(hv.z * uv.z, SMIN);
        v.w = fmaxf(hv.w * uv.w, SMIN);
        vals[i] = v;
        s += (v.x + v.y) + (v.z + v.w);
    }
    s = block_row_sum(s);
    const float inv = 1.f / fmaxf(s, 1e-20f);
    float4* op = (float4*)(hout + (size_t)row * FOUT);
    unsigned int* bp = h8u + (size_t)row * (FOUT / 4);
    #pragma unroll
    for (int i = 0; i < 2; ++i) {
        float4 v = vals[i];
        v.x *= inv; v.y *= inv; v.z *= inv; v.w *= inv;
        op[i * 256 + threadIdx.x] = v;
        unsigned int u = 0;
        u = (unsigned int)__builtin_amdgcn_cvt_pk_fp8_f32(v.x * HSCALE, v.y * HSCALE, (int)u, false);
        u = (unsigned int)__builtin_amdgcn_cvt_pk_fp8_f32(v.z * HSCALE, v.w * HSCALE, (int)u, true);
        bp[i * 256 + threadIdx.x] = u;
    }
}

extern "C" void kernel_launch(void* const* d_in, const int* in_sizes, int n_in,
                              void* d_out, int out_size, void* d_ws, size_t ws_size,
                              hipStream_t stream) {
    const float* x = (const float*)d_in[0];
    const float* W = (const float*)d_in[1];
    float* out = (float*)d_out;

    const size_t RECON_PART = (size_t)B_DIM * FIN * 2;   // bf16, 16.78 MB
    const size_t UPD_PART   = (size_t)B_DIM * FOUT * 4;  // fp32, 16.78 MB
    const size_t FIXED      = 81000000;                  // non-partial buffers (~80 MB)
    int S1 = 1, S2 = 1;
    if (ws_size >= FIXED + 2 * RECON_PART + 4 * UPD_PART + (1 << 20)) {
        S1 = 2; S2 = 4;
    }

    char* ws = (char*)d_ws;
    size_t off = 0;
    auto alloc = [&](size_t bytes) {
        void* p = ws + off;
        off += (bytes + 255) & ~(size_t)255;
        return p;
    };
    unsigned short* Wn   = (unsigned short*)alloc((size_t)FOUT * FIN * 2); // 16.8 MB
    unsigned char*  WnT8 = (unsigned char*)alloc((size_t)FIN * FOUT);      // 8.4 MB
    unsigned int*   h8u  = (unsigned int*)alloc((size_t)B_DIM * FOUT);     // 4.2 MB
    unsigned int*   rbf  = (unsigned int*)alloc((size_t)B_DIM * FIN * 2);  // 16.8 MB
    unsigned int*   xnb  = (unsigned int*)alloc((size_t)B_DIM * FIN * 2);  // 16.8 MB
    float* h             = (float*)alloc((size_t)B_DIM * FOUT * 4);        // 16.8 MB
    unsigned short* rec  = (unsigned short*)alloc(RECON_PART * S1);
    float* upd           = (float*)alloc(UPD_PART * S2);
    (void)in_sizes; (void)n_in; (void)out_size;

    k_norm_w<<<FOUT, 256, 0, stream>>>(W, Wn);
    k_transpose_fp8<<<dim3(FIN / 32, FOUT / 32), dim3(32, 8), 0, stream>>>(Wn, WnT8);
    k_norm_x<<<B_DIM, 256, 0, stream>>>(x, xnb);
    k_init_h<<<(B_DIM * FOUT) / (256 * 4), 256, 0, stream>>>(h, h8u);

    for (int it = 0; it < NITER; ++it) {
        // recon = h @ Wn : fp8 NT, A=h8 (K=FOUT), B=WnT8 (FIN x FOUT), bf16 partials
        k_gemm_fp8<<<dim3(FIN / 128, B_DIM / 128, S1), 256, 0, stream>>>(
            (const unsigned char*)h8u, WnT8, rec, FIN, FOUT, FOUT / S1);
        k_make_ratio<<<B_DIM, 256, 0, stream>>>(rec, S1, xnb, rbf);
        // upd = r @ Wn^T : bf16 NT 256x256 8-phase, A=rbf (K=FIN), B=Wn, fp32 partials
        k_gemm_nt256<<<dim3(FOUT / 256, B_DIM / 256, S2), 512, 0, stream>>>(
            (const unsigned short*)rbf, Wn, upd, FOUT, FIN, FIN / S2);
        k_update_h<<<B_DIM, 256, 0, stream>>>(h, upd, S2, (it == NITER - 1) ? out : h, h8u);
    }
}

// Round 2
// 1104.074 us; speedup vs baseline: 1.1056x; 1.0885x over previous
//
#include <hip/hip_runtime.h>
#include <stdint.h>
#include <stddef.h>

#define B_DIM 2048
#define FIN   4096
#define FOUT  2048
#define NITER 10
#define SMIN  1e-5f

// fp8 pre-scales (exact powers of 2): Wn*2^14 <= ~17, h*2^8 <= 256 < 448 (e4m3 max)
#define WSCALE 16384.0f
#define HSCALE 256.0f
#define OUTSCALE (1.0f / 4194304.0f)   // 2^-22

typedef float floatx16 __attribute__((ext_vector_type(16)));
typedef short bf16x8   __attribute__((ext_vector_type(8)));

__device__ inline unsigned short f2bf(float f) {
    unsigned int u = __float_as_uint(f);
    u += 0x7fffu + ((u >> 16) & 1u);
    return (unsigned short)(u >> 16);
}
__device__ inline float bflo(unsigned int u) { return __uint_as_float(u << 16); }
__device__ inline float bfhi(unsigned int u) { return __uint_as_float(u & 0xffff0000u); }
__device__ inline unsigned int pack2(float a, float b) {
    return (unsigned int)f2bf(a) | ((unsigned int)f2bf(b) << 16);
}

__device__ inline void async16(const void* g, void* l) {
    __builtin_amdgcn_global_load_lds(
        (const __attribute__((address_space(1))) void*)g,
        (__attribute__((address_space(3))) void*)l, 16, 0, 0);
}

__device__ inline float block_row_sum(float v) {
    #pragma unroll
    for (int o = 32; o > 0; o >>= 1) v += __shfl_down(v, o, 64);
    __shared__ float red[4];
    const int lane = threadIdx.x & 63, w = threadIdx.x >> 6;
    if (lane == 0) red[w] = v;
    __syncthreads();
    return red[0] + red[1] + red[2] + red[3];
}

// Wn = clip(W,1e-5)/rowsum -> bf16 (FOUT x FIN)  [bf16 master, used by GEMM2 + fp8 transpose]
__global__ __launch_bounds__(256) void k_norm_w(const float* __restrict__ W,
                                                unsigned short* __restrict__ Wn) {
    const int row = blockIdx.x;
    const float4* src = (const float4*)(W + (size_t)row * FIN);
    float4 vals[4];
    float s = 0.f;
    #pragma unroll
    for (int i = 0; i < 4; ++i) {
        float4 v = src[i * 256 + threadIdx.x];
        v.x = fmaxf(v.x, SMIN); v.y = fmaxf(v.y, SMIN);
        v.z = fmaxf(v.z, SMIN); v.w = fmaxf(v.w, SMIN);
        vals[i] = v;
        s += (v.x + v.y) + (v.z + v.w);
    }
    s = block_row_sum(s);
    const float inv = 1.f / fmaxf(s, 1e-20f);
    ushort4* dst = (ushort4*)(Wn + (size_t)row * FIN);
    #pragma unroll
    for (int i = 0; i < 4; ++i) {
        float4 v = vals[i];
        ushort4 o;
        o.x = f2bf(v.x * inv); o.y = f2bf(v.y * inv);
        o.z = f2bf(v.z * inv); o.w = f2bf(v.w * inv);
        dst[i * 256 + threadIdx.x] = o;
    }
}

// xn = x / rowsum(x) -> bf16 packed (B x FIN)
__global__ __launch_bounds__(256) void k_norm_x(const float* __restrict__ x,
                                                unsigned int* __restrict__ xnb) {
    const int row = blockIdx.x;
    const float4* src = (const float4*)(x + (size_t)row * FIN);
    float4 vals[4];
    float s = 0.f;
    #pragma unroll
    for (int j = 0; j < 2; ++j) {
        const int idx = j * 256 + threadIdx.x;
        float4 a = src[2 * idx], b = src[2 * idx + 1];
        vals[2 * j] = a; vals[2 * j + 1] = b;
        s += (fabsf(a.x) + fabsf(a.y)) + (fabsf(a.z) + fabsf(a.w));
        s += (fabsf(b.x) + fabsf(b.y)) + (fabsf(b.z) + fabsf(b.w));
    }
    s = block_row_sum(s);
    const float inv = 1.f / fmaxf(s, 1e-20f);
    uint4* dst = (uint4*)(xnb + (size_t)row * (FIN / 2));
    #pragma unroll
    for (int j = 0; j < 2; ++j) {
        float4 a = vals[2 * j], b = vals[2 * j + 1];
        uint4 o;
        o.x = pack2(a.x * inv, a.y * inv);
        o.y = pack2(a.z * inv, a.w * inv);
        o.z = pack2(b.x * inv, b.y * inv);
        o.w = pack2(b.z * inv, b.w * inv);
        dst[j * 256 + threadIdx.x] = o;
    }
}

// WnT8[i][o] = fp8(Wn[o][i] * 2^14)   (B operand of GEMM1, fp8 e4m3)
__global__ __launch_bounds__(256) void k_transpose_fp8(const unsigned short* __restrict__ src,
                                                       unsigned char* __restrict__ dst) {
    __shared__ unsigned short tile[32][33];
    const int bi = blockIdx.x * 32, bo = blockIdx.y * 32;
    const int tx = threadIdx.x, ty = threadIdx.y;  // (32,8)
    #pragma unroll
    for (int j = 0; j < 4; ++j)
        tile[ty + j * 8][tx] = src[(size_t)(bo + ty + j * 8) * FIN + bi + tx];
    __syncthreads();
    #pragma unroll
    for (int j = 0; j < 4; ++j) {
        const float v = bflo((unsigned int)tile[tx][ty + j * 8]) * WSCALE;
        const unsigned int b = (unsigned int)__builtin_amdgcn_cvt_pk_fp8_f32(v, v, 0, false) & 0xffu;
        dst[(size_t)(bi + ty + j * 8) * FOUT + bo + tx] = (unsigned char)b;
    }
}

// h0 = 1/FOUT: fp32 master + fp8(h*2^8) = fp8(0.125) = 0x20 exactly
__global__ __launch_bounds__(256) void k_init_h(float* __restrict__ h,
                                                unsigned int* __restrict__ h8u) {
    const int i = blockIdx.x * blockDim.x + threadIdx.x;
    const float hv = 1.f / (float)FOUT;
    float4 v; v.x = hv; v.y = hv; v.z = hv; v.w = hv;
    ((float4*)h)[i] = v;
    h8u[i] = 0x20202020u;
}

// GEMM1 (fp8): rec = (h8 * WnT8^T) * 2^-22 -> bf16.
// NT, no split-K (R2), 128x128 tile, BK=64, 4 waves each 64x64 = 2x2 of
// v_mfma_f32_32x32x16_fp8_fp8 (K=16, i64 operands = 8 fp8/lane, k=half*8+j).
// XCD supertile (R2): grid (32N,16M) -> 512 blocks, linearId%8 = XCD; XCD j
// owns an 8Mx8N block rectangle so its L2 streams 8 A-panels + 8 B-panels
// k-slice-synchronized with its 64 resident blocks.
__global__ __launch_bounds__(256) void k_gemm_fp8(const unsigned char* __restrict__ A,
                                                  const unsigned char* __restrict__ Bm,
                                                  unsigned short* __restrict__ C,
                                                  int N, int K) {
    __shared__ __align__(16) unsigned char As[128 * 64];  // 8 KB
    __shared__ __align__(16) unsigned char Bs[128 * 64];  // 8 KB
    const int tid  = threadIdx.x;
    const int wave = tid >> 6;
    const int lane = tid & 63;

    // XCD supertile remap (grid 32x16): j = id%8 -> rect (j>>2)*8 M, (j&3)*8 N
    const int id = blockIdx.y * 32 + blockIdx.x;   // 0..511
    const int j8 = id & 7, s = id >> 3;            // s in [0,64)
    const int bm = ((j8 >> 2) * 8 + (s >> 3)) * 128;   // 16 M-blocks
    const int bn = ((j8 & 3) * 8 + (s & 7)) * 128;     // 32 N-blocks

    const int wr = (wave >> 1) * 64;
    const int wc = (wave & 1) * 64;
    const int l31 = lane & 31;
    const int half = lane >> 5;

    floatx16 acc[2][2] = {};

    const int lr = lane >> 2;
    const int ks = ((lane & 3) ^ ((lane >> 3) & 3)) * 16;  // bytes
    const unsigned char* ga = A  + (size_t)(bm + wave * 32 + lr) * K + ks;
    const unsigned char* gb = Bm + (size_t)(bn + wave * 32 + lr) * K + ks;

    for (int k0 = 0; k0 < K; k0 += 64) {
        __syncthreads();
        #pragma unroll
        for (int j = 0; j < 2; ++j) {
            async16(ga + (size_t)j * 16 * K + k0, &As[wave * 2048 + j * 1024]);
            async16(gb + (size_t)j * 16 * K + k0, &Bs[wave * 2048 + j * 1024]);
        }
        __syncthreads();

        const int sw = (l31 >> 1) & 3;
        #pragma unroll
        for (int kk = 0; kk < 4; ++kk) {
            const int off = ((kk ^ sw) << 4) + (half << 3);
            long long af[2], bf[2];
            #pragma unroll
            for (int t = 0; t < 2; ++t) {
                af[t] = *(const long long*)&As[(wr + t * 32 + l31) * 64 + off];
                bf[t] = *(const long long*)&Bs[(wc + t * 32 + l31) * 64 + off];
            }
            #pragma unroll
            for (int mt = 0; mt < 2; ++mt)
                #pragma unroll
                for (int nt = 0; nt < 2; ++nt)
                    acc[mt][nt] = __builtin_amdgcn_mfma_f32_32x32x16_fp8_fp8(
                        af[mt], bf[nt], acc[mt][nt], 0, 0, 0);
        }
    }

    const int row0 = 4 * half;
    #pragma unroll
    for (int mt = 0; mt < 2; ++mt) {
        #pragma unroll
        for (int nt = 0; nt < 2; ++nt) {
            #pragma unroll
            for (int reg = 0; reg < 16; ++reg) {
                const int rr = bm + wr + mt * 32 + row0 + (reg & 3) + 8 * (reg >> 2);
                const int cc = bn + wc + nt * 32 + l31;
                C[(size_t)rr * N + cc] = f2bf(acc[mt][nt][reg] * OUTSCALE);
            }
        }
    }
}

// GEMM2 (bf16): upd_z = rbf * Wn^T, fp32 partials. R2: split-K S2=2 (one
// dispatch, z in-grid -> 512 co-resident blocks, 2/CU), 128x128 tile, BK=64,
// 4 waves each 64x64 = 2x2 of v_mfma_f32_32x32x16_bf16 (proven 2-phase loop).
// XCD supertile: per-z grid 16x16; XCD j owns a 4Mx8N rectangle.
__global__ __launch_bounds__(256) void k_gemm_nt(const unsigned short* __restrict__ A,
                                                 const unsigned short* __restrict__ Bm,
                                                 float* __restrict__ C,
                                                 int N, int K, int Ksub) {
    __shared__ __align__(16) unsigned short As[128 * 64];  // 16 KB
    __shared__ __align__(16) unsigned short Bs[128 * 64];  // 16 KB
    const int tid  = threadIdx.x;
    const int wave = tid >> 6;
    const int lane = tid & 63;

    // XCD supertile remap (per-z grid 16x16): j = id%8 -> 4Mx8N rectangle
    const int id = blockIdx.y * 16 + blockIdx.x;   // 0..255 (z*256 = 0 mod 8)
    const int j8 = id & 7, s = id >> 3;            // s in [0,32)
    const int bm = ((j8 >> 1) * 4 + (s >> 3)) * 128;   // 16 M-blocks
    const int bn = ((j8 & 1) * 8 + (s & 7)) * 128;     // 16 N-blocks

    const int kz = blockIdx.z * Ksub;
    const int wr = (wave >> 1) * 64;
    const int wc = (wave & 1) * 64;
    const int l31 = lane & 31;
    const int half = lane >> 5;

    floatx16 acc[2][2] = {};

    const int lr = lane >> 3;
    const int ks = ((lane & 7) ^ lr) * 8;   // shorts
    const unsigned short* ga = A  + (size_t)(bm + wave * 32 + lr) * K + ks;
    const unsigned short* gb = Bm + (size_t)(bn + wave * 32 + lr) * K + ks;

    for (int k0 = kz; k0 < kz + Ksub; k0 += 64) {
        __syncthreads();
        #pragma unroll
        for (int j = 0; j < 4; ++j) {
            async16(ga + (size_t)j * 8 * K + k0, &As[wave * 2048 + j * 512]);
            async16(gb + (size_t)j * 8 * K + k0, &Bs[wave * 2048 + j * 512]);
        }
        __syncthreads();

        #pragma unroll
        for (int kk = 0; kk < 4; ++kk) {
            const int slot = ((kk * 2 + half) ^ (l31 & 7)) * 8;
            bf16x8 af[2], bf[2];
            #pragma unroll
            for (int t = 0; t < 2; ++t) {
                af[t] = *(const bf16x8*)&As[(wr + t * 32 + l31) * 64 + slot];
                bf[t] = *(const bf16x8*)&Bs[(wc + t * 32 + l31) * 64 + slot];
            }
            #pragma unroll
            for (int mt = 0; mt < 2; ++mt)
                #pragma unroll
                for (int nt = 0; nt < 2; ++nt)
                    acc[mt][nt] = __builtin_amdgcn_mfma_f32_32x32x16_bf16(
                        af[mt], bf[nt], acc[mt][nt], 0, 0, 0);
        }
    }

    float* Cz = C + (size_t)blockIdx.z * B_DIM * N;
    const int row0 = 4 * half;
    #pragma unroll
    for (int mt = 0; mt < 2; ++mt) {
        #pragma unroll
        for (int nt = 0; nt < 2; ++nt) {
            #pragma unroll
            for (int reg = 0; reg < 16; ++reg) {
                const int rr = bm + wr + mt * 32 + row0 + (reg & 3) + 8 * (reg >> 2);
                const int cc = bn + wc + nt * 32 + l31;
                Cz[(size_t)rr * N + cc] = acc[mt][nt][reg];
            }
        }
    }
}

// recon (single bf16 buffer); s = rowsum(clip); r = xn*s/clip -> bf16
__global__ __launch_bounds__(256) void k_make_ratio(const unsigned short* __restrict__ rec,
                                                    int nparts,
                                                    const unsigned int* __restrict__ xnb,
                                                    unsigned int* __restrict__ r) {
    const int row = blockIdx.x;
    float v[16];
    float s = 0.f;
    #pragma unroll
    for (int g = 0; g < 2; ++g) {
        const int idx = g * 256 + threadIdx.x;
        uint4 u = ((const uint4*)(rec + (size_t)row * FIN))[idx];
        float* p = v + g * 8;
        p[0] = bflo(u.x); p[1] = bfhi(u.x); p[2] = bflo(u.y); p[3] = bfhi(u.y);
        p[4] = bflo(u.z); p[5] = bfhi(u.z); p[6] = bflo(u.w); p[7] = bfhi(u.w);
        for (int z = 1; z < nparts; ++z) {
            uint4 q = ((const uint4*)(rec + (size_t)z * B_DIM * FIN + (size_t)row * FIN))[idx];
            p[0] += bflo(q.x); p[1] += bfhi(q.x); p[2] += bflo(q.y); p[3] += bfhi(q.y);
            p[4] += bflo(q.z); p[5] += bfhi(q.z); p[6] += bflo(q.w); p[7] += bfhi(q.w);
        }
        #pragma unroll
        for (int e = 0; e < 8; ++e) { p[e] = fmaxf(p[e], SMIN); s += p[e]; }
    }
    s = block_row_sum(s);
    #pragma unroll
    for (int g = 0; g < 2; ++g) {
        const int idx = g * 256 + threadIdx.x;
        uint4 xu = ((const uint4*)(xnb + (size_t)row * (FIN / 2)))[idx];
        float* p = v + g * 8;
        uint4 o;
        o.x = pack2(bflo(xu.x) * s / p[0], bfhi(xu.x) * s / p[1]);
        o.y = pack2(bflo(xu.y) * s / p[2], bfhi(xu.y) * s / p[3]);
        o.z = pack2(bflo(xu.z) * s / p[4], bfhi(xu.z) * s / p[5]);
        o.w = pack2(bflo(xu.w) * s / p[6], bfhi(xu.w) * s / p[7]);
        ((uint4*)(r + (size_t)row * (FIN / 2)))[idx] = o;
    }
}

// upd = sum fp32 partials; t = clip(h*upd); h' = t/rowsum(t); fp32 master + fp8(h*2^8)
__global__ __launch_bounds__(256) void k_update_h(const float* __restrict__ hin,
                                                  const float* __restrict__ upd,
                                                  int nparts,
                                                  float* __restrict__ hout,
                                                  unsigned int* __restrict__ h8u) {
    const int row = blockIdx.x;
    const float4* hp = (const float4*)(hin + (size_t)row * FOUT);
    float4 vals[2];
    float s = 0.f;
    #pragma unroll
    for (int i = 0; i < 2; ++i) {
        const int idx = i * 256 + threadIdx.x;
        float4 hv = hp[idx];
        float4 uv = ((const float4*)(upd + (size_t)row * FOUT))[idx];
        for (int z = 1; z < nparts; ++z) {
            float4 p = ((const float4*)(upd + (size_t)z * B_DIM * FOUT + (size_t)row * FOUT))[idx];
            uv.x += p.x; uv.y += p.y; uv.z += p.z; uv.w += p.w;
        }
        float4 v;
        v.x = fmaxf(hv.x * uv.x, SMIN);
        v.y = fmaxf(hv.y * uv.y, SMIN);
        v.z = fmaxf(hv.z * uv.z, SMIN);
        v.w = fmaxf(hv.w * uv.w, SMIN);
        vals[i] = v;
        s += (v.x + v.y) + (v.z + v.w);
    }
    s = block_row_sum(s);
    const float inv = 1.f / fmaxf(s, 1e-20f);
    float4* op = (float4*)(hout + (size_t)row * FOUT);
    unsigned int* bp = h8u + (size_t)row * (FOUT / 4);
    #pragma unroll
    for (int i = 0; i < 2; ++i) {
        float4 v = vals[i];
        v.x *= inv; v.y *= inv; v.z *= inv; v.w *= inv;
        op[i * 256 + threadIdx.x] = v;
        unsigned int u = 0;
        u = (unsigned int)__builtin_amdgcn_cvt_pk_fp8_f32(v.x * HSCALE, v.y * HSCALE, (int)u, false);
        u = (unsigned int)__builtin_amdgcn_cvt_pk_fp8_f32(v.z * HSCALE, v.w * HSCALE, (int)u, true);
        bp[i * 256 + threadIdx.x] = u;
    }
}

extern "C" void kernel_launch(void* const* d_in, const int* in_sizes, int n_in,
                              void* d_out, int out_size, void* d_ws, size_t ws_size,
                              hipStream_t stream) {
    const float* x = (const float*)d_in[0];
    const float* W = (const float*)d_in[1];
    float* out = (float*)d_out;

    const size_t RECON_SZ = (size_t)B_DIM * FIN * 2;   // bf16, 16.78 MB
    const size_t UPD_PART = (size_t)B_DIM * FOUT * 4;  // fp32, 16.78 MB
    const size_t FIXED    = 81000000;                  // non-partial buffers (~80 MB)
    int S2 = 1;
    if (ws_size >= FIXED + RECON_SZ + 2 * UPD_PART + (1 << 20)) {
        S2 = 2;
    }

    char* ws = (char*)d_ws;
    size_t off = 0;
    auto alloc = [&](size_t bytes) {
        void* p = ws + off;
        off += (bytes + 255) & ~(size_t)255;
        return p;
    };
    unsigned short* Wn   = (unsigned short*)alloc((size_t)FOUT * FIN * 2); // 16.8 MB
    unsigned char*  WnT8 = (unsigned char*)alloc((size_t)FIN * FOUT);      // 8.4 MB
    unsigned int*   h8u  = (unsigned int*)alloc((size_t)B_DIM * FOUT);     // 4.2 MB
    unsigned int*   rbf  = (unsigned int*)alloc((size_t)B_DIM * FIN * 2);  // 16.8 MB
    unsigned int*   xnb  = (unsigned int*)alloc((size_t)B_DIM * FIN * 2);  // 16.8 MB
    float* h             = (float*)alloc((size_t)B_DIM * FOUT * 4);        // 16.8 MB
    unsigned short* rec  = (unsigned short*)alloc(RECON_SZ);
    float* upd           = (float*)alloc(UPD_PART * S2);
    (void)in_sizes; (void)n_in; (void)out_size;

    k_norm_w<<<FOUT, 256, 0, stream>>>(W, Wn);
    k_transpose_fp8<<<dim3(FIN / 32, FOUT / 32), dim3(32, 8), 0, stream>>>(Wn, WnT8);
    k_norm_x<<<B_DIM, 256, 0, stream>>>(x, xnb);
    k_init_h<<<(B_DIM * FOUT) / (256 * 4), 256, 0, stream>>>(h, h8u);

    for (int it = 0; it < NITER; ++it) {
        // recon = h @ Wn : fp8 NT, no split-K, A=h8 (K=FOUT), B=WnT8, bf16 out
        k_gemm_fp8<<<dim3(FIN / 128, B_DIM / 128, 1), 256, 0, stream>>>(
            (const unsigned char*)h8u, WnT8, rec, FIN, FOUT);
        k_make_ratio<<<B_DIM, 256, 0, stream>>>(rec, 1, xnb, rbf);
        // upd = r @ Wn^T : bf16 NT, split-K=2 in-grid, A=rbf (K=FIN), B=Wn
        k_gemm_nt<<<dim3(FOUT / 128, B_DIM / 128, S2), 256, 0, stream>>>(
            (const unsigned short*)rbf, Wn, upd, FOUT, FIN, FIN / S2);
        k_update_h<<<B_DIM, 256, 0, stream>>>(h, upd, S2, (it == NITER - 1) ? out : h, h8u);
    }
}

// Round 3
// 985.824 us; speedup vs baseline: 1.2382x; 1.1200x over previous
//
#include <hip/hip_runtime.h>
#include <stdint.h>
#include <stddef.h>

#define B_DIM 2048
#define FIN   4096
#define FOUT  2048
#define NITER 10
#define SMIN  1e-5f

// fp8 pre-scales (exact powers of 2): Wn*2^14 <= ~17, h*2^8 <= 256 < 448 (e4m3 max)
#define WSCALE 16384.0f
#define HSCALE 256.0f
#define OUTSCALE (1.0f / 4194304.0f)   // 2^-22

typedef float floatx16 __attribute__((ext_vector_type(16)));
typedef short bf16x8   __attribute__((ext_vector_type(8)));
typedef int   intx4    __attribute__((ext_vector_type(4)));
typedef int   intx8    __attribute__((ext_vector_type(8)));

__device__ inline unsigned short f2bf(float f) {
    unsigned int u = __float_as_uint(f);
    u += 0x7fffu + ((u >> 16) & 1u);
    return (unsigned short)(u >> 16);
}
__device__ inline float bflo(unsigned int u) { return __uint_as_float(u << 16); }
__device__ inline float bfhi(unsigned int u) { return __uint_as_float(u & 0xffff0000u); }
__device__ inline unsigned int pack2(float a, float b) {
    return (unsigned int)f2bf(a) | ((unsigned int)f2bf(b) << 16);
}

__device__ inline void async16(const void* g, void* l) {
    __builtin_amdgcn_global_load_lds(
        (const __attribute__((address_space(1))) void*)g,
        (__attribute__((address_space(3))) void*)l, 16, 0, 0);
}

__device__ inline float block_row_sum(float v) {
    #pragma unroll
    for (int o = 32; o > 0; o >>= 1) v += __shfl_down(v, o, 64);
    __shared__ float red[4];
    const int lane = threadIdx.x & 63, w = threadIdx.x >> 6;
    if (lane == 0) red[w] = v;
    __syncthreads();
    return red[0] + red[1] + red[2] + red[3];
}

// Wn = clip(W,1e-5)/rowsum -> bf16 (FOUT x FIN)  [bf16 master, used by GEMM2 + fp8 transpose]
__global__ __launch_bounds__(256) void k_norm_w(const float* __restrict__ W,
                                                unsigned short* __restrict__ Wn) {
    const int row = blockIdx.x;
    const float4* src = (const float4*)(W + (size_t)row * FIN);
    float4 vals[4];
    float s = 0.f;
    #pragma unroll
    for (int i = 0; i < 4; ++i) {
        float4 v = src[i * 256 + threadIdx.x];
        v.x = fmaxf(v.x, SMIN); v.y = fmaxf(v.y, SMIN);
        v.z = fmaxf(v.z, SMIN); v.w = fmaxf(v.w, SMIN);
        vals[i] = v;
        s += (v.x + v.y) + (v.z + v.w);
    }
    s = block_row_sum(s);
    const float inv = 1.f / fmaxf(s, 1e-20f);
    ushort4* dst = (ushort4*)(Wn + (size_t)row * FIN);
    #pragma unroll
    for (int i = 0; i < 4; ++i) {
        float4 v = vals[i];
        ushort4 o;
        o.x = f2bf(v.x * inv); o.y = f2bf(v.y * inv);
        o.z = f2bf(v.z * inv); o.w = f2bf(v.w * inv);
        dst[i * 256 + threadIdx.x] = o;
    }
}

// xn = x / rowsum(x) -> bf16 packed (B x FIN)
__global__ __launch_bounds__(256) void k_norm_x(const float* __restrict__ x,
                                                unsigned int* __restrict__ xnb) {
    const int row = blockIdx.x;
    const float4* src = (const float4*)(x + (size_t)row * FIN);
    float4 vals[4];
    float s = 0.f;
    #pragma unroll
    for (int j = 0; j < 2; ++j) {
        const int idx = j * 256 + threadIdx.x;
        float4 a = src[2 * idx], b = src[2 * idx + 1];
        vals[2 * j] = a; vals[2 * j + 1] = b;
        s += (fabsf(a.x) + fabsf(a.y)) + (fabsf(a.z) + fabsf(a.w));
        s += (fabsf(b.x) + fabsf(b.y)) + (fabsf(b.z) + fabsf(b.w));
    }
    s = block_row_sum(s);
    const float inv = 1.f / fmaxf(s, 1e-20f);
    uint4* dst = (uint4*)(xnb + (size_t)row * (FIN / 2));
    #pragma unroll
    for (int j = 0; j < 2; ++j) {
        float4 a = vals[2 * j], b = vals[2 * j + 1];
        uint4 o;
        o.x = pack2(a.x * inv, a.y * inv);
        o.y = pack2(a.z * inv, a.w * inv);
        o.z = pack2(b.x * inv, b.y * inv);
        o.w = pack2(b.z * inv, b.w * inv);
        dst[j * 256 + threadIdx.x] = o;
    }
}

// WnT8[i][o] = fp8(Wn[o][i] * 2^14)   (B operand of GEMM1, fp8 e4m3)
__global__ __launch_bounds__(256) void k_transpose_fp8(const unsigned short* __restrict__ src,
                                                       unsigned char* __restrict__ dst) {
    __shared__ unsigned short tile[32][33];
    const int bi = blockIdx.x * 32, bo = blockIdx.y * 32;
    const int tx = threadIdx.x, ty = threadIdx.y;  // (32,8)
    #pragma unroll
    for (int j = 0; j < 4; ++j)
        tile[ty + j * 8][tx] = src[(size_t)(bo + ty + j * 8) * FIN + bi + tx];
    __syncthreads();
    #pragma unroll
    for (int j = 0; j < 4; ++j) {
        const float v = bflo((unsigned int)tile[tx][ty + j * 8]) * WSCALE;
        const unsigned int b = (unsigned int)__builtin_amdgcn_cvt_pk_fp8_f32(v, v, 0, false) & 0xffu;
        dst[(size_t)(bi + ty + j * 8) * FOUT + bo + tx] = (unsigned char)b;
    }
}

// h0 = 1/FOUT: fp32 master + fp8(h*2^8) = fp8(0.125) = 0x20 exactly
__global__ __launch_bounds__(256) void k_init_h(float* __restrict__ h,
                                                unsigned int* __restrict__ h8u) {
    const int i = blockIdx.x * blockDim.x + threadIdx.x;
    const float hv = 1.f / (float)FOUT;
    float4 v; v.x = hv; v.y = hv; v.z = hv; v.w = hv;
    ((float4*)h)[i] = v;
    h8u[i] = 0x20202020u;
}

// GEMM1 (MX fp8, R3): rec = (h8 * WnT8^T) * 2^-22 -> bf16.
// NT, no split-K, 128x128 tile, BK=64, 4 waves each 64x64 = 2x2 of
// v_mfma_scale_f32_32x32x64_f8f6f4 (FMT=fp8, scales=1.0 in every byte ->
// opsel-proof). One MFMA eats the whole K=64 tile: lane q=lane>>5 holds
// bytes [q*32,q*32+32) of its row; A and B use the IDENTICAL (row,k-byte)
// mapping, so any internal k-permutation cancels (same symmetry as the
// verified 32x32x16 path). 2x MFMA rate vs non-scaled fp8 (4686 vs 2190 TF).
// XCD supertile: grid (32N,16M) -> 512 blocks; XCD j owns 8Mx8N rectangle.
__global__ __launch_bounds__(256) void k_gemm_fp8(const unsigned char* __restrict__ A,
                                                  const unsigned char* __restrict__ Bm,
                                                  unsigned short* __restrict__ C,
                                                  int N, int K) {
    __shared__ __align__(16) unsigned char As[128 * 64];  // 8 KB
    __shared__ __align__(16) unsigned char Bs[128 * 64];  // 8 KB
    const int tid  = threadIdx.x;
    const int wave = tid >> 6;
    const int lane = tid & 63;

    // XCD supertile remap (grid 32x16): j = id%8 -> rect (j>>2)*8 M, (j&3)*8 N
    const int id = blockIdx.y * 32 + blockIdx.x;   // 0..511
    const int j8 = id & 7, s = id >> 3;            // s in [0,64)
    const int bm = ((j8 >> 2) * 8 + (s >> 3)) * 128;   // 16 M-blocks
    const int bn = ((j8 & 3) * 8 + (s & 7)) * 128;     // 32 N-blocks

    const int wr = (wave >> 1) * 64;
    const int wc = (wave & 1) * 64;
    const int l31 = lane & 31;
    const int half = lane >> 5;

    floatx16 acc[2][2] = {};

    // staging (unchanged, R0-verified): lane -> row lr=lane>>2, 16B slot
    // lane&3; global 16B chunk kc = slot ^ ((lr>>1)&3); LDS linear.
    const int lr = lane >> 2;
    const int ks = ((lane & 3) ^ ((lane >> 3) & 3)) * 16;  // bytes
    const unsigned char* ga = A  + (size_t)(bm + wave * 32 + lr) * K + ks;
    const unsigned char* gb = Bm + (size_t)(bn + wave * 32 + lr) * K + ks;

    for (int k0 = 0; k0 < K; k0 += 64) {
        __syncthreads();
        #pragma unroll
        for (int j = 0; j < 2; ++j) {
            async16(ga + (size_t)j * 16 * K + k0, &As[wave * 2048 + j * 1024]);
            async16(gb + (size_t)j * 16 * K + k0, &Bs[wave * 2048 + j * 1024]);
        }
        __syncthreads();

        // fragment: lane needs global chunks 2*half, 2*half+1 of its row;
        // stored at slot g ^ sw, sw = (row>>1)&3 (wr/wc/t*32 are 0 mod 8).
        const int sw = (l31 >> 1) & 3;
        const int c0 = (((half << 1) | 0) ^ sw) << 4;
        const int c1 = (((half << 1) | 1) ^ sw) << 4;
        intx8 af[2], bf[2];
        #pragma unroll
        for (int t = 0; t < 2; ++t) {
            const int ra = (wr + t * 32 + l31) * 64;
            const int rb = (wc + t * 32 + l31) * 64;
            intx4 a0 = *(const intx4*)&As[ra + c0];
            intx4 a1 = *(const intx4*)&As[ra + c1];
            intx4 b0 = *(const intx4*)&Bs[rb + c0];
            intx4 b1 = *(const intx4*)&Bs[rb + c1];
            af[t] = (intx8){a0.x, a0.y, a0.z, a0.w, a1.x, a1.y, a1.z, a1.w};
            bf[t] = (intx8){b0.x, b0.y, b0.z, b0.w, b1.x, b1.y, b1.z, b1.w};
        }
        #pragma unroll
        for (int mt = 0; mt < 2; ++mt)
            #pragma unroll
            for (int nt = 0; nt < 2; ++nt)
                acc[mt][nt] = __builtin_amdgcn_mfma_scale_f32_32x32x64_f8f6f4(
                    af[mt], bf[nt], acc[mt][nt],
                    0, 0,                      // cbsz=fp8, blgp=fp8
                    0, 0x7F7F7F7Fu,            // scale_a opsel, e8m0 1.0 all bytes
                    0, 0x7F7F7F7Fu);           // scale_b opsel, e8m0 1.0 all bytes
    }

    const int row0 = 4 * half;
    #pragma unroll
    for (int mt = 0; mt < 2; ++mt) {
        #pragma unroll
        for (int nt = 0; nt < 2; ++nt) {
            #pragma unroll
            for (int reg = 0; reg < 16; ++reg) {
                const int rr = bm + wr + mt * 32 + row0 + (reg & 3) + 8 * (reg >> 2);
                const int cc = bn + wc + nt * 32 + l31;
                C[(size_t)rr * N + cc] = f2bf(acc[mt][nt][reg] * OUTSCALE);
            }
        }
    }
}

// GEMM2 (bf16): upd_z = rbf * Wn^T, fp32 partials. Split-K S2=2 (one
// dispatch, z in-grid -> 512 co-resident blocks, 2/CU), 128x128 tile, BK=64,
// 4 waves each 64x64 = 2x2 of v_mfma_f32_32x32x16_bf16 (proven 2-phase loop).
// XCD supertile: per-z grid 16x16; XCD j owns a 4Mx8N rectangle.
__global__ __launch_bounds__(256) void k_gemm_nt(const unsigned short* __restrict__ A,
                                                 const unsigned short* __restrict__ Bm,
                                                 float* __restrict__ C,
                                                 int N, int K, int Ksub) {
    __shared__ __align__(16) unsigned short As[128 * 64];  // 16 KB
    __shared__ __align__(16) unsigned short Bs[128 * 64];  // 16 KB
    const int tid  = threadIdx.x;
    const int wave = tid >> 6;
    const int lane = tid & 63;

    // XCD supertile remap (per-z grid 16x16): j = id%8 -> 4Mx8N rectangle
    const int id = blockIdx.y * 16 + blockIdx.x;   // 0..255 (z*256 = 0 mod 8)
    const int j8 = id & 7, s = id >> 3;            // s in [0,32)
    const int bm = ((j8 >> 1) * 4 + (s >> 3)) * 128;   // 16 M-blocks
    const int bn = ((j8 & 1) * 8 + (s & 7)) * 128;     // 16 N-blocks

    const int kz = blockIdx.z * Ksub;
    const int wr = (wave >> 1) * 64;
    const int wc = (wave & 1) * 64;
    const int l31 = lane & 31;
    const int half = lane >> 5;

    floatx16 acc[2][2] = {};

    const int lr = lane >> 3;
    const int ks = ((lane & 7) ^ lr) * 8;   // shorts
    const unsigned short* ga = A  + (size_t)(bm + wave * 32 + lr) * K + ks;
    const unsigned short* gb = Bm + (size_t)(bn + wave * 32 + lr) * K + ks;

    for (int k0 = kz; k0 < kz + Ksub; k0 += 64) {
        __syncthreads();
        #pragma unroll
        for (int j = 0; j < 4; ++j) {
            async16(ga + (size_t)j * 8 * K + k0, &As[wave * 2048 + j * 512]);
            async16(gb + (size_t)j * 8 * K + k0, &Bs[wave * 2048 + j * 512]);
        }
        __syncthreads();

        #pragma unroll
        for (int kk = 0; kk < 4; ++kk) {
            const int slot = ((kk * 2 + half) ^ (l31 & 7)) * 8;
            bf16x8 af[2], bf[2];
            #pragma unroll
            for (int t = 0; t < 2; ++t) {
                af[t] = *(const bf16x8*)&As[(wr + t * 32 + l31) * 64 + slot];
                bf[t] = *(const bf16x8*)&Bs[(wc + t * 32 + l31) * 64 + slot];
            }
            #pragma unroll
            for (int mt = 0; mt < 2; ++mt)
                #pragma unroll
                for (int nt = 0; nt < 2; ++nt)
                    acc[mt][nt] = __builtin_amdgcn_mfma_f32_32x32x16_bf16(
                        af[mt], bf[nt], acc[mt][nt], 0, 0, 0);
        }
    }

    float* Cz = C + (size_t)blockIdx.z * B_DIM * N;
    const int row0 = 4 * half;
    #pragma unroll
    for (int mt = 0; mt < 2; ++mt) {
        #pragma unroll
        for (int nt = 0; nt < 2; ++nt) {
            #pragma unroll
            for (int reg = 0; reg < 16; ++reg) {
                const int rr = bm + wr + mt * 32 + row0 + (reg & 3) + 8 * (reg >> 2);
                const int cc = bn + wc + nt * 32 + l31;
                Cz[(size_t)rr * N + cc] = acc[mt][nt][reg];
            }
        }
    }
}

// recon (single bf16 buffer); s = rowsum(clip); r = xn*s/clip -> bf16
__global__ __launch_bounds__(256) void k_make_ratio(const unsigned short* __restrict__ rec,
                                                    int nparts,
                                                    const unsigned int* __restrict__ xnb,
                                                    unsigned int* __restrict__ r) {
    const int row = blockIdx.x;
    float v[16];
    float s = 0.f;
    #pragma unroll
    for (int g = 0; g < 2; ++g) {
        const int idx = g * 256 + threadIdx.x;
        uint4 u = ((const uint4*)(rec + (size_t)row * FIN))[idx];
        float* p = v + g * 8;
        p[0] = bflo(u.x); p[1] = bfhi(u.x); p[2] = bflo(u.y); p[3] = bfhi(u.y);
        p[4] = bflo(u.z); p[5] = bfhi(u.z); p[6] = bflo(u.w); p[7] = bfhi(u.w);
        for (int z = 1; z < nparts; ++z) {
            uint4 q = ((const uint4*)(rec + (size_t)z * B_DIM * FIN + (size_t)row * FIN))[idx];
            p[0] += bflo(q.x); p[1] += bfhi(q.x); p[2] += bflo(q.y); p[3] += bfhi(q.y);
            p[4] += bflo(q.z); p[5] += bfhi(q.z); p[6] += bflo(q.w); p[7] += bfhi(q.w);
        }
        #pragma unroll
        for (int e = 0; e < 8; ++e) { p[e] = fmaxf(p[e], SMIN); s += p[e]; }
    }
    s = block_row_sum(s);
    #pragma unroll
    for (int g = 0; g < 2; ++g) {
        const int idx = g * 256 + threadIdx.x;
        uint4 xu = ((const uint4*)(xnb + (size_t)row * (FIN / 2)))[idx];
        float* p = v + g * 8;
        uint4 o;
        o.x = pack2(bflo(xu.x) * s / p[0], bfhi(xu.x) * s / p[1]);
        o.y = pack2(bflo(xu.y) * s / p[2], bfhi(xu.y) * s / p[3]);
        o.z = pack2(bflo(xu.z) * s / p[4], bfhi(xu.z) * s / p[5]);
        o.w = pack2(bflo(xu.w) * s / p[6], bfhi(xu.w) * s / p[7]);
        ((uint4*)(r + (size_t)row * (FIN / 2)))[idx] = o;
    }
}

// upd = sum fp32 partials; t = clip(h*upd); h' = t/rowsum(t); fp32 master + fp8(h*2^8)
__global__ __launch_bounds__(256) void k_update_h(const float* __restrict__ hin,
                                                  const float* __restrict__ upd,
                                                  int nparts,
                                                  float* __restrict__ hout,
                                                  unsigned int* __restrict__ h8u) {
    const int row = blockIdx.x;
    const float4* hp = (const float4*)(hin + (size_t)row * FOUT);
    float4 vals[2];
    float s = 0.f;
    #pragma unroll
    for (int i = 0; i < 2; ++i) {
        const int idx = i * 256 + threadIdx.x;
        float4 hv = hp[idx];
        float4 uv = ((const float4*)(upd + (size_t)row * FOUT))[idx];
        for (int z = 1; z < nparts; ++z) {
            float4 p = ((const float4*)(upd + (size_t)z * B_DIM * FOUT + (size_t)row * FOUT))[idx];
            uv.x += p.x; uv.y += p.y; uv.z += p.z; uv.w += p.w;
        }
        float4 v;
        v.x = fmaxf(hv.x * uv.x, SMIN);
        v.y = fmaxf(hv.y * uv.y, SMIN);
        v.z = fmaxf(hv.z * uv.z, SMIN);
        v.w = fmaxf(hv.w * uv.w, SMIN);
        vals[i] = v;
        s += (v.x + v.y) + (v.z + v.w);
    }
    s = block_row_sum(s);
    const float inv = 1.f / fmaxf(s, 1e-20f);
    float4* op = (float4*)(hout + (size_t)row * FOUT);
    unsigned int* bp = h8u + (size_t)row * (FOUT / 4);
    #pragma unroll
    for (int i = 0; i < 2; ++i) {
        float4 v = vals[i];
        v.x *= inv; v.y *= inv; v.z *= inv; v.w *= inv;
        op[i * 256 + threadIdx.x] = v;
        unsigned int u = 0;
        u = (unsigned int)__builtin_amdgcn_cvt_pk_fp8_f32(v.x * HSCALE, v.y * HSCALE, (int)u, false);
        u = (unsigned int)__builtin_amdgcn_cvt_pk_fp8_f32(v.z * HSCALE, v.w * HSCALE, (int)u, true);
        bp[i * 256 + threadIdx.x] = u;
    }
}

extern "C" void kernel_launch(void* const* d_in, const int* in_sizes, int n_in,
                              void* d_out, int out_size, void* d_ws, size_t ws_size,
                              hipStream_t stream) {
    const float* x = (const float*)d_in[0];
    const float* W = (const float*)d_in[1];
    float* out = (float*)d_out;

    const size_t RECON_SZ = (size_t)B_DIM * FIN * 2;   // bf16, 16.78 MB
    const size_t UPD_PART = (size_t)B_DIM * FOUT * 4;  // fp32, 16.78 MB
    const size_t FIXED    = 81000000;                  // non-partial buffers (~80 MB)
    int S2 = 1;
    if (ws_size >= FIXED + RECON_SZ + 2 * UPD_PART + (1 << 20)) {
        S2 = 2;
    }

    char* ws = (char*)d_ws;
    size_t off = 0;
    auto alloc = [&](size_t bytes) {
        void* p = ws + off;
        off += (bytes + 255) & ~(size_t)255;
        return p;
    };
    unsigned short* Wn   = (unsigned short*)alloc((size_t)FOUT * FIN * 2); // 16.8 MB
    unsigned char*  WnT8 = (unsigned char*)alloc((size_t)FIN * FOUT);      // 8.4 MB
    unsigned int*   h8u  = (unsigned int*)alloc((size_t)B_DIM * FOUT);     // 4.2 MB
    unsigned int*   rbf  = (unsigned int*)alloc((size_t)B_DIM * FIN * 2);  // 16.8 MB
    unsigned int*   xnb  = (unsigned int*)alloc((size_t)B_DIM * FIN * 2);  // 16.8 MB
    float* h             = (float*)alloc((size_t)B_DIM * FOUT * 4);        // 16.8 MB
    unsigned short* rec  = (unsigned short*)alloc(RECON_SZ);
    float* upd           = (float*)alloc(UPD_PART * S2);
    (void)in_sizes; (void)n_in; (void)out_size;

    k_norm_w<<<FOUT, 256, 0, stream>>>(W, Wn);
    k_transpose_fp8<<<dim3(FIN / 32, FOUT / 32), dim3(32, 8), 0, stream>>>(Wn, WnT8);
    k_norm_x<<<B_DIM, 256, 0, stream>>>(x, xnb);
    k_init_h<<<(B_DIM * FOUT) / (256 * 4), 256, 0, stream>>>(h, h8u);

    for (int it = 0; it < NITER; ++it) {
        // recon = h @ Wn : MX fp8 NT, no split-K, A=h8 (K=FOUT), B=WnT8, bf16 out
        k_gemm_fp8<<<dim3(FIN / 128, B_DIM / 128, 1), 256, 0, stream>>>(
            (const unsigned char*)h8u, WnT8, rec, FIN, FOUT);
        k_make_ratio<<<B_DIM, 256, 0, stream>>>(rec, 1, xnb, rbf);
        // upd = r @ Wn^T : bf16 NT, split-K=2 in-grid, A=rbf (K=FIN), B=Wn
        k_gemm_nt<<<dim3(FOUT / 128, B_DIM / 128, S2), 256, 0, stream>>>(
            (const unsigned short*)rbf, Wn, upd, FOUT, FIN, FIN / S2);
        k_update_h<<<B_DIM, 256, 0, stream>>>(h, upd, S2, (it == NITER - 1) ? out : h, h8u);
    }
}

// Round 5
// 846.788 us; speedup vs baseline: 1.4415x; 1.1642x over previous
//
#include <hip/hip_runtime.h>
#include <stdint.h>
#include <stddef.h>

#define B_DIM 2048
#define FIN   4096
#define FOUT  2048
#define NITER 10
#define SMIN  1e-5f

// GEMM1 fp8 pre-scales (exact powers of 2): Wn*2^14 <= ~16 < 448, h*2^8 <= 256 < 448
#define WSCALE 16384.0f
#define HSCALE 256.0f
#define OUTSCALE1 (1.0f / 4194304.0f)   // 2^-22 = 1/(WSCALE*HSCALE)
// GEMM2 i8 scales: ratio*56 <= ~118 < 127; Wn per-row 126/wmax
#define RS_I8 56.0f

typedef float floatx16 __attribute__((ext_vector_type(16)));
typedef int   intx4    __attribute__((ext_vector_type(4)));
typedef int   intx8    __attribute__((ext_vector_type(8)));
typedef int   intx16   __attribute__((ext_vector_type(16)));

__device__ inline unsigned short f2bf(float f) {
    unsigned int u = __float_as_uint(f);
    u += 0x7fffu + ((u >> 16) & 1u);
    return (unsigned short)(u >> 16);
}
__device__ inline float bflo(unsigned int u) { return __uint_as_float(u << 16); }
__device__ inline float bfhi(unsigned int u) { return __uint_as_float(u & 0xffff0000u); }
__device__ inline unsigned int pack2(float a, float b) {
    return (unsigned int)f2bf(a) | ((unsigned int)f2bf(b) << 16);
}

__device__ inline void async16(const void* g, void* l) {
    __builtin_amdgcn_global_load_lds(
        (const __attribute__((address_space(1))) void*)g,
        (__attribute__((address_space(3))) void*)l, 16, 0, 0);
}

__device__ inline float block_row_sum(float v) {
    #pragma unroll
    for (int o = 32; o > 0; o >>= 1) v += __shfl_down(v, o, 64);
    __shared__ float red[4];
    const int lane = threadIdx.x & 63, w = threadIdx.x >> 6;
    if (lane == 0) red[w] = v;
    __syncthreads();
    return red[0] + red[1] + red[2] + red[3];
}

__device__ inline void block_sum_max(float s, float m, float* os, float* om) {
    #pragma unroll
    for (int o = 32; o > 0; o >>= 1) {
        s += __shfl_down(s, o, 64);
        m = fmaxf(m, __shfl_down(m, o, 64));
    }
    __shared__ float rs[4], rm[4];
    const int lane = threadIdx.x & 63, w = threadIdx.x >> 6;
    if (lane == 0) { rs[w] = s; rm[w] = m; }
    __syncthreads();
    *os = (rs[0] + rs[1]) + (rs[2] + rs[3]);
    *om = fmaxf(fmaxf(rm[0], rm[1]), fmaxf(rm[2], rm[3]));
}

// R5: per W-row: s = rowsum(clip), m = rowmax(clip).
//   Wn8  = fp8(clip/s * 2^14)            (GEMM1 B via transpose; aliased w/ rec)
//   WnI8 = i8(clip * 126/m) in [0,126]   (GEMM2 B, per-row uniform quant)
//   dq   = m / (126 * 56 * s)            (GEMM2 per-output-col dequant)
__global__ __launch_bounds__(256) void k_norm_w(const float* __restrict__ W,
                                                unsigned char* __restrict__ Wn8,
                                                unsigned char* __restrict__ WnI8,
                                                float* __restrict__ dq) {
    const int row = blockIdx.x;
    const float4* src = (const float4*)(W + (size_t)row * FIN);
    float4 vals[4];
    float s = 0.f, m = 0.f;
    #pragma unroll
    for (int i = 0; i < 4; ++i) {
        float4 v = src[i * 256 + threadIdx.x];
        v.x = fmaxf(v.x, SMIN); v.y = fmaxf(v.y, SMIN);
        v.z = fmaxf(v.z, SMIN); v.w = fmaxf(v.w, SMIN);
        vals[i] = v;
        s += (v.x + v.y) + (v.z + v.w);
        m = fmaxf(m, fmaxf(fmaxf(v.x, v.y), fmaxf(v.z, v.w)));
    }
    block_sum_max(s, m, &s, &m);
    s = fmaxf(s, 1e-20f);
    const float inv8 = WSCALE / s;
    const float qi = 126.f / m;
    if (threadIdx.x == 0) dq[row] = m / (126.f * RS_I8 * s);
    unsigned int* d8 = (unsigned int*)(Wn8 + (size_t)row * FIN);
    unsigned int* di = (unsigned int*)(WnI8 + (size_t)row * FIN);
    #pragma unroll
    for (int i = 0; i < 4; ++i) {
        float4 v = vals[i];
        unsigned int u = 0;
        u = (unsigned int)__builtin_amdgcn_cvt_pk_fp8_f32(v.x * inv8, v.y * inv8, (int)u, false);
        u = (unsigned int)__builtin_amdgcn_cvt_pk_fp8_f32(v.z * inv8, v.w * inv8, (int)u, true);
        d8[i * 256 + threadIdx.x] = u;
        const int b0 = (int)(v.x * qi + 0.5f);
        const int b1 = (int)(v.y * qi + 0.5f);
        const int b2 = (int)(v.z * qi + 0.5f);
        const int b3 = (int)(v.w * qi + 0.5f);
        di[i * 256 + threadIdx.x] =
            (unsigned int)b0 | ((unsigned int)b1 << 8) |
            ((unsigned int)b2 << 16) | ((unsigned int)b3 << 24);
    }
}

// xn = x / rowsum(x) -> bf16 packed (B x FIN)
__global__ __launch_bounds__(256) void k_norm_x(const float* __restrict__ x,
                                                unsigned int* __restrict__ xnb) {
    const int row = blockIdx.x;
    const float4* src = (const float4*)(x + (size_t)row * FIN);
    float4 vals[4];
    float s = 0.f;
    #pragma unroll
    for (int j = 0; j < 2; ++j) {
        const int idx = j * 256 + threadIdx.x;
        float4 a = src[2 * idx], b = src[2 * idx + 1];
        vals[2 * j] = a; vals[2 * j + 1] = b;
        s += (fabsf(a.x) + fabsf(a.y)) + (fabsf(a.z) + fabsf(a.w));
        s += (fabsf(b.x) + fabsf(b.y)) + (fabsf(b.z) + fabsf(b.w));
    }
    s = block_row_sum(s);
    const float inv = 1.f / fmaxf(s, 1e-20f);
    uint4* dst = (uint4*)(xnb + (size_t)row * (FIN / 2));
    #pragma unroll
    for (int j = 0; j < 2; ++j) {
        float4 a = vals[2 * j], b = vals[2 * j + 1];
        uint4 o;
        o.x = pack2(a.x * inv, a.y * inv);
        o.y = pack2(a.z * inv, a.w * inv);
        o.z = pack2(b.x * inv, b.y * inv);
        o.w = pack2(b.z * inv, b.w * inv);
        dst[j * 256 + threadIdx.x] = o;
    }
}

// WnT8[i][o] = Wn8[o][i]  (pure byte transpose; B operand of GEMM1)
__global__ __launch_bounds__(256) void k_transpose_fp8(const unsigned char* __restrict__ src,
                                                       unsigned char* __restrict__ dst) {
    __shared__ unsigned char tile[32][33];
    const int bi = blockIdx.x * 32, bo = blockIdx.y * 32;
    const int tx = threadIdx.x, ty = threadIdx.y;  // (32,8)
    #pragma unroll
    for (int j = 0; j < 4; ++j)
        tile[ty + j * 8][tx] = src[(size_t)(bo + ty + j * 8) * FIN + bi + tx];
    __syncthreads();
    #pragma unroll
    for (int j = 0; j < 4; ++j)
        dst[(size_t)(bi + ty + j * 8) * FOUT + bo + tx] = tile[tx][ty + j * 8];
}

// h0 = 1/FOUT: fp32 master + fp8(h*2^8) = fp8(0.125) = 0x20 exactly
__global__ __launch_bounds__(256) void k_init_h(float* __restrict__ h,
                                                unsigned int* __restrict__ h8u) {
    const int i = blockIdx.x * blockDim.x + threadIdx.x;
    const float hv = 1.f / (float)FOUT;
    float4 v; v.x = hv; v.y = hv; v.z = hv; v.w = hv;
    ((float4*)h)[i] = v;
    h8u[i] = 0x20202020u;
}

// GEMM1 (MX fp8, R3-validated): rec = (h8 * WnT8^T) * 2^-22 -> bf16.
// NT, no split-K, 128x128 tile, BK=64, 4 waves each 64x64 = 2x2 of
// v_mfma_scale_f32_32x32x64_f8f6f4 (FMT=fp8, scales = e8m0 1.0 all bytes).
// A/B use the identical (row,k-byte) mapping so internal k-permutation cancels.
// XCD supertile: grid (32N,16M) -> 512 blocks; XCD j owns 8Mx8N rectangle.
__global__ __launch_bounds__(256) void k_gemm_fp8(const unsigned char* __restrict__ A,
                                                  const unsigned char* __restrict__ Bm,
                                                  unsigned short* __restrict__ C,
                                                  int N, int K) {
    __shared__ __align__(16) unsigned char As[128 * 64];  // 8 KB
    __shared__ __align__(16) unsigned char Bs[128 * 64];  // 8 KB
    const int tid  = threadIdx.x;
    const int wave = tid >> 6;
    const int lane = tid & 63;

    const int id = blockIdx.y * 32 + blockIdx.x;   // 0..511
    const int j8 = id & 7, s = id >> 3;            // s in [0,64)
    const int bm = ((j8 >> 2) * 8 + (s >> 3)) * 128;   // 16 M-blocks
    const int bn = ((j8 & 3) * 8 + (s & 7)) * 128;     // 32 N-blocks

    const int wr = (wave >> 1) * 64;
    const int wc = (wave & 1) * 64;
    const int l31 = lane & 31;
    const int half = lane >> 5;

    floatx16 acc[2][2] = {};

    const int lr = lane >> 2;
    const int ks = ((lane & 3) ^ ((lane >> 3) & 3)) * 16;  // bytes
    const unsigned char* ga = A  + (size_t)(bm + wave * 32 + lr) * K + ks;
    const unsigned char* gb = Bm + (size_t)(bn + wave * 32 + lr) * K + ks;

    for (int k0 = 0; k0 < K; k0 += 64) {
        __syncthreads();
        #pragma unroll
        for (int j = 0; j < 2; ++j) {
            async16(ga + (size_t)j * 16 * K + k0, &As[wave * 2048 + j * 1024]);
            async16(gb + (size_t)j * 16 * K + k0, &Bs[wave * 2048 + j * 1024]);
        }
        __syncthreads();

        const int sw = (l31 >> 1) & 3;
        const int c0 = (((half << 1) | 0) ^ sw) << 4;
        const int c1 = (((half << 1) | 1) ^ sw) << 4;
        intx8 af[2], bf[2];
        #pragma unroll
        for (int t = 0; t < 2; ++t) {
            const int ra = (wr + t * 32 + l31) * 64;
            const int rb = (wc + t * 32 + l31) * 64;
            intx4 a0 = *(const intx4*)&As[ra + c0];
            intx4 a1 = *(const intx4*)&As[ra + c1];
            intx4 b0 = *(const intx4*)&Bs[rb + c0];
            intx4 b1 = *(const intx4*)&Bs[rb + c1];
            af[t] = (intx8){a0.x, a0.y, a0.z, a0.w, a1.x, a1.y, a1.z, a1.w};
            bf[t] = (intx8){b0.x, b0.y, b0.z, b0.w, b1.x, b1.y, b1.z, b1.w};
        }
        #pragma unroll
        for (int mt = 0; mt < 2; ++mt)
            #pragma unroll
            for (int nt = 0; nt < 2; ++nt)
                acc[mt][nt] = __builtin_amdgcn_mfma_scale_f32_32x32x64_f8f6f4(
                    af[mt], bf[nt], acc[mt][nt],
                    0, 0, 0, 0x7F7F7F7Fu, 0, 0x7F7F7F7Fu);
    }

    const int row0 = 4 * half;
    #pragma unroll
    for (int mt = 0; mt < 2; ++mt) {
        #pragma unroll
        for (int nt = 0; nt < 2; ++nt) {
            #pragma unroll
            for (int reg = 0; reg < 16; ++reg) {
                const int rr = bm + wr + mt * 32 + row0 + (reg & 3) + 8 * (reg >> 2);
                const int cc = bn + wc + nt * 32 + l31;
                C[(size_t)rr * N + cc] = f2bf(acc[mt][nt][reg] * OUTSCALE1);
            }
        }
    }
}

// GEMM2 (i8, R5): upd_z = (ri8 * WnI8^T) * dq[col], fp32 partials.
// v_mfma_i32_32x32x32_i8 (K=32, intx4 = 16 i8/lane, lane-half q takes 16B
// chunk kk*2+q) -- i32 accumulate EXACT; rate ~4404 TOPS ~= MX-fp8 parity.
// Uniform-quantized nonneg operands: ratio*56 in [0,127], Wn*126/rowmax in
// [0,126] -- ~4x less quant error than fp8 e4m3 (R4 failed at 1.53e-5).
// A/B symmetric (row,k-byte) mapping -> internal k-permutation cancels.
// Split-K S2=2 in-grid -> 512 blocks (2/CU); XCD supertile 4Mx8N per XCD.
__global__ __launch_bounds__(256) void k_gemm_i8(const unsigned char* __restrict__ A,
                                                 const unsigned char* __restrict__ Bm,
                                                 const float* __restrict__ dq,
                                                 float* __restrict__ C,
                                                 int N, int K, int Ksub) {
    __shared__ __align__(16) unsigned char As[128 * 64];  // 8 KB
    __shared__ __align__(16) unsigned char Bs[128 * 64];  // 8 KB
    const int tid  = threadIdx.x;
    const int wave = tid >> 6;
    const int lane = tid & 63;

    const int id = blockIdx.y * 16 + blockIdx.x;   // 0..255 (z*256 = 0 mod 8)
    const int j8 = id & 7, s = id >> 3;            // s in [0,32)
    const int bm = ((j8 >> 1) * 4 + (s >> 3)) * 128;   // 16 M-blocks
    const int bn = ((j8 & 1) * 8 + (s & 7)) * 128;     // 16 N-blocks

    const int kz = blockIdx.z * Ksub;
    const int wr = (wave >> 1) * 64;
    const int wc = (wave & 1) * 64;
    const int l31 = lane & 31;
    const int half = lane >> 5;

    intx16 acc[2][2] = {};

    const int lr = lane >> 2;
    const int ks = ((lane & 3) ^ ((lane >> 3) & 3)) * 16;  // bytes
    const unsigned char* ga = A  + (size_t)(bm + wave * 32 + lr) * K + ks;
    const unsigned char* gb = Bm + (size_t)(bn + wave * 32 + lr) * K + ks;

    for (int k0 = kz; k0 < kz + Ksub; k0 += 64) {
        __syncthreads();
        #pragma unroll
        for (int j = 0; j < 2; ++j) {
            async16(ga + (size_t)j * 16 * K + k0, &As[wave * 2048 + j * 1024]);
            async16(gb + (size_t)j * 16 * K + k0, &Bs[wave * 2048 + j * 1024]);
        }
        __syncthreads();

        const int sw = (l31 >> 1) & 3;
        #pragma unroll
        for (int kk = 0; kk < 2; ++kk) {
            // MFMA kk covers K bytes [kk*32, kk*32+32); lane-half q holds
            // chunk kk*2+q (16 bytes), stored at slot (kk*2+q)^sw.
            const int slot = (((kk << 1) + half) ^ sw) << 4;
            intx4 af[2], bf[2];
            #pragma unroll
            for (int t = 0; t < 2; ++t) {
                af[t] = *(const intx4*)&As[(wr + t * 32 + l31) * 64 + slot];
                bf[t] = *(const intx4*)&Bs[(wc + t * 32 + l31) * 64 + slot];
            }
            #pragma unroll
            for (int mt = 0; mt < 2; ++mt)
                #pragma unroll
                for (int nt = 0; nt < 2; ++nt)
                    acc[mt][nt] = __builtin_amdgcn_mfma_i32_32x32x32_i8(
                        af[mt], bf[nt], acc[mt][nt], 0, 0, 0);
        }
    }

    float* Cz = C + (size_t)blockIdx.z * B_DIM * N;
    const int row0 = 4 * half;
    const float d0 = dq[bn + wc + l31];        // nt=0 column
    const float d1 = dq[bn + wc + 32 + l31];   // nt=1 column
    #pragma unroll
    for (int mt = 0; mt < 2; ++mt) {
        #pragma unroll
        for (int nt = 0; nt < 2; ++nt) {
            const float d = nt ? d1 : d0;
            #pragma unroll
            for (int reg = 0; reg < 16; ++reg) {
                const int rr = bm + wr + mt * 32 + row0 + (reg & 3) + 8 * (reg >> 2);
                const int cc = bn + wc + nt * 32 + l31;
                Cz[(size_t)rr * N + cc] = (float)acc[mt][nt][reg] * d;
            }
        }
    }
}

// recon (bf16); s = rowsum(clip); ri8 = i8(min(xn*s*56/clip, 127))
__global__ __launch_bounds__(256) void k_make_ratio(const unsigned short* __restrict__ rec,
                                                    const unsigned int* __restrict__ xnb,
                                                    unsigned char* __restrict__ ri8) {
    const int row = blockIdx.x;
    float v[16];
    float s = 0.f;
    #pragma unroll
    for (int g = 0; g < 2; ++g) {
        const int idx = g * 256 + threadIdx.x;
        uint4 u = ((const uint4*)(rec + (size_t)row * FIN))[idx];
        float* p = v + g * 8;
        p[0] = bflo(u.x); p[1] = bfhi(u.x); p[2] = bflo(u.y); p[3] = bfhi(u.y);
        p[4] = bflo(u.z); p[5] = bfhi(u.z); p[6] = bflo(u.w); p[7] = bfhi(u.w);
        #pragma unroll
        for (int e = 0; e < 8; ++e) { p[e] = fmaxf(p[e], SMIN); s += p[e]; }
    }
    s = block_row_sum(s);
    const float ss = s * RS_I8;
    #pragma unroll
    for (int g = 0; g < 2; ++g) {
        const int idx = g * 256 + threadIdx.x;
        uint4 xu = ((const uint4*)(xnb + (size_t)row * (FIN / 2)))[idx];
        float* p = v + g * 8;
        float r[8];
        r[0] = bflo(xu.x) * ss / p[0]; r[1] = bfhi(xu.x) * ss / p[1];
        r[2] = bflo(xu.y) * ss / p[2]; r[3] = bfhi(xu.y) * ss / p[3];
        r[4] = bflo(xu.z) * ss / p[4]; r[5] = bfhi(xu.z) * ss / p[5];
        r[6] = bflo(xu.w) * ss / p[6]; r[7] = bfhi(xu.w) * ss / p[7];
        unsigned int q[8];
        #pragma unroll
        for (int e = 0; e < 8; ++e)
            q[e] = (unsigned int)(int)(fminf(r[e], 127.0f) + 0.5f);
        uint2 o;
        o.x = q[0] | (q[1] << 8) | (q[2] << 16) | (q[3] << 24);
        o.y = q[4] | (q[5] << 8) | (q[6] << 16) | (q[7] << 24);
        ((uint2*)(ri8 + (size_t)row * FIN))[idx] = o;
    }
}

// upd = sum fp32 partials; t = clip(h*upd); h' = t/rowsum(t); fp32 master + fp8(h*2^8)
__global__ __launch_bounds__(256) void k_update_h(const float* __restrict__ hin,
                                                  const float* __restrict__ upd,
                                                  int nparts,
                                                  float* __restrict__ hout,
                                                  unsigned int* __restrict__ h8u) {
    const int row = blockIdx.x;
    const float4* hp = (const float4*)(hin + (size_t)row * FOUT);
    float4 vals[2];
    float s = 0.f;
    #pragma unroll
    for (int i = 0; i < 2; ++i) {
        const int idx = i * 256 + threadIdx.x;
        float4 hv = hp[idx];
        float4 uv = ((const float4*)(upd + (size_t)row * FOUT))[idx];
        for (int z = 1; z < nparts; ++z) {
            float4 p = ((const float4*)(upd + (size_t)z * B_DIM * FOUT + (size_t)row * FOUT))[idx];
            uv.x += p.x; uv.y += p.y; uv.z += p.z; uv.w += p.w;
        }
        float4 v;
        v.x = fmaxf(hv.x * uv.x, SMIN);
        v.y = fmaxf(hv.y * uv.y, SMIN);
        v.z = fmaxf(hv.z * uv.z, SMIN);
        v.w = fmaxf(hv.w * uv.w, SMIN);
        vals[i] = v;
        s += (v.x + v.y) + (v.z + v.w);
    }
    s = block_row_sum(s);
    const float inv = 1.f / fmaxf(s, 1e-20f);
    float4* op = (float4*)(hout + (size_t)row * FOUT);
    unsigned int* bp = h8u + (size_t)row * (FOUT / 4);
    #pragma unroll
    for (int i = 0; i < 2; ++i) {
        float4 v = vals[i];
        v.x *= inv; v.y *= inv; v.z *= inv; v.w *= inv;
        op[i * 256 + threadIdx.x] = v;
        unsigned int u = 0;
        u = (unsigned int)__builtin_amdgcn_cvt_pk_fp8_f32(v.x * HSCALE, v.y * HSCALE, (int)u, false);
        u = (unsigned int)__builtin_amdgcn_cvt_pk_fp8_f32(v.z * HSCALE, v.w * HSCALE, (int)u, true);
        bp[i * 256 + threadIdx.x] = u;
    }
}

extern "C" void kernel_launch(void* const* d_in, const int* in_sizes, int n_in,
                              void* d_out, int out_size, void* d_ws, size_t ws_size,
                              hipStream_t stream) {
    const float* x = (const float*)d_in[0];
    const float* W = (const float*)d_in[1];
    float* out = (float*)d_out;

    const size_t UPD_PART = (size_t)B_DIM * FOUT * 4;  // fp32, 16.78 MB
    const size_t FIXED    = 81000000;                  // non-partial buffers
    int S2 = 1;
    if (ws_size >= FIXED + 2 * UPD_PART + (1 << 20)) {
        S2 = 2;
    }

    char* ws = (char*)d_ws;
    size_t off = 0;
    auto alloc = [&](size_t bytes) {
        void* p = ws + off;
        off += (bytes + 255) & ~(size_t)255;
        return p;
    };
    unsigned char*  WnT8 = (unsigned char*)alloc((size_t)FIN * FOUT);      // 8.4 MB
    unsigned char*  WnI8 = (unsigned char*)alloc((size_t)FOUT * FIN);      // 8.4 MB
    float*          dq   = (float*)alloc((size_t)FOUT * 4);                // 8 KB
    unsigned int*   h8u  = (unsigned int*)alloc((size_t)B_DIM * FOUT);     // 4.2 MB
    unsigned char*  ri8  = (unsigned char*)alloc((size_t)B_DIM * FIN);     // 8.4 MB
    unsigned int*   xnb  = (unsigned int*)alloc((size_t)B_DIM * FIN * 2);  // 16.8 MB
    float* h             = (float*)alloc((size_t)B_DIM * FOUT * 4);        // 16.8 MB
    unsigned short* rec  = (unsigned short*)alloc((size_t)B_DIM * FIN * 2);// 16.8 MB
    float* upd           = (float*)alloc(UPD_PART * S2);
    // Wn8 (fp8 master for the GEMM1 transpose) aliases rec: only live during
    // setup, before GEMM1 ever writes rec.
    unsigned char* Wn8 = (unsigned char*)rec;
    (void)in_sizes; (void)n_in; (void)out_size;

    k_norm_w<<<FOUT, 256, 0, stream>>>(W, Wn8, WnI8, dq);
    k_transpose_fp8<<<dim3(FIN / 32, FOUT / 32), dim3(32, 8), 0, stream>>>(Wn8, WnT8);
    k_norm_x<<<B_DIM, 256, 0, stream>>>(x, xnb);
    k_init_h<<<(B_DIM * FOUT) / (256 * 4), 256, 0, stream>>>(h, h8u);

    for (int it = 0; it < NITER; ++it) {
        // recon = h @ Wn : MX fp8 NT, A=h8 (K=FOUT), B=WnT8, bf16 out
        k_gemm_fp8<<<dim3(FIN / 128, B_DIM / 128, 1), 256, 0, stream>>>(
            (const unsigned char*)h8u, WnT8, rec, FIN, FOUT);
        k_make_ratio<<<B_DIM, 256, 0, stream>>>(rec, xnb, ri8);
        // upd = r @ Wn^T : i8 NT, split-K=2 in-grid, A=ri8 (K=FIN), B=WnI8
        k_gemm_i8<<<dim3(FOUT / 128, B_DIM / 128, S2), 256, 0, stream>>>(
            ri8, WnI8, dq, upd, FOUT, FIN, FIN / S2);
        k_update_h<<<B_DIM, 256, 0, stream>>>(h, upd, S2, (it == NITER - 1) ? out : h, h8u);
    }
}